// Round 14
// baseline (203.401 us; speedup 1.0000x reference)
//
#include <hip/hip_runtime.h>
#include <hip/hip_bf16.h>

typedef __attribute__((ext_vector_type(4))) float f32x4;
typedef __attribute__((ext_vector_type(4))) int   i32x4;
typedef __attribute__((ext_vector_type(8))) int   i32x8;

#define N_ROWS 8192
#define B_HALF 4096
#define NUT   2080          // 64*65/2 upper-triangle 128x128 tiles
// exp(2S) where acc = 256*S (inputs pre-scaled x16): exp2(acc * 2*log2e/256)
#define EXP2C4 0.01127105500694503f
#define SCL1   0x7F7F7F7Fu  // E8M0 127 in all bytes -> scale 1.0

// ws layout (bytes)
#define WS_ZN       0                    // fp4 frag-major [512 groups][2048 B] = 1 MB
#define WS_ROWACC   2097152              // float[8192]  sum_j exp(2 S_ij)
#define WS_POS      2129920              // float[8192]  raw acc_pos (= 256*S_pos)
#define WS_DIAG     2162688              // float[8192]  exp2(acc_ii*EXP2C4)
#define WS_CNT      2195460              // uint  tile completion counter

__device__ __forceinline__ float fexp2(float x) {
#if __has_builtin(__builtin_amdgcn_exp2f)
    return __builtin_amdgcn_exp2f(x);
#else
    return exp2f(x);
#endif
}

// round-to-nearest e2m1 code (values 0,.5,1,1.5,2,3,4,6), sign in bit 3
__device__ __forceinline__ unsigned int q4(float x) {
    float a = fabsf(x);
    unsigned int s = (__float_as_uint(x) >> 31) << 3;
    unsigned int c = a < 0.25f ? 0u : a < 0.75f ? 1u : a < 1.25f ? 2u
                   : a < 1.75f ? 3u : a < 2.5f  ? 4u : a < 3.5f  ? 5u
                   : a < 5.0f  ? 6u : 7u;
    return c | s;
}

__device__ __forceinline__ i32x8 widen(i32x4 v) {
    return (i32x8){v.x, v.y, v.z, v.w, 0, 0, 0, 0};
}

// 16-lane row sum on the VALU pipe (DPP row_shr). Result in lane 15 of row.
__device__ __forceinline__ float dpp_rowsum16(float x) {
    x += __int_as_float(__builtin_amdgcn_update_dpp(
             0, __float_as_int(x), 0x111, 0xF, 0xF, true));   // row_shr:1
    x += __int_as_float(__builtin_amdgcn_update_dpp(
             0, __float_as_int(x), 0x112, 0xF, 0xF, true));   // row_shr:2
    x += __int_as_float(__builtin_amdgcn_update_dpp(
             0, __float_as_int(x), 0x114, 0xF, 0xF, true));   // row_shr:4
    x += __int_as_float(__builtin_amdgcn_update_dpp(
             0, __float_as_int(x), 0x118, 0xF, 0xF, true));   // row_shr:8
    return x;
}

__device__ __forceinline__ void async_copy16(const void* g, void* l) {
    __builtin_amdgcn_global_load_lds(
        (const __attribute__((address_space(1))) unsigned int*)g,
        (__attribute__((address_space(3))) unsigned int*)l,
        16, 0, 0);
}

// ---------------- Phase 1: normalize -> fp4 (x16), FRAGMENT-MAJOR ------------
// (validated R10-R13)
__global__ __launch_bounds__(256) void normalize_k(
    const float* __restrict__ z_orig, const float* __restrict__ z_aug,
    unsigned char* __restrict__ zn, float* __restrict__ rowAcc,
    unsigned int* __restrict__ cnt)
{
    if (blockIdx.x == 0 && threadIdx.x == 0) { *cnt = 0u; }
    const int row  = blockIdx.x * 4 + (threadIdx.x >> 6);
    const int lane = threadIdx.x & 63;
    if (lane == 0) rowAcc[row] = 0.0f;       // zeroed before tile_k (stream order)
    const float* src = (row < B_HALF) ? (z_aug  + (size_t)row * 256)
                                      : (z_orig + (size_t)(row - B_HALF) * 256);
    float4 v = ((const float4*)src)[lane];
    float ss = v.x*v.x + v.y*v.y + v.z*v.z + v.w*v.w;
    #pragma unroll
    for (int m = 1; m < 64; m <<= 1) ss += __shfl_xor(ss, m);
    float inv = 16.0f / fmaxf(sqrtf(ss), 1e-8f);   // x16 pre-scale into e2m1 range
    unsigned int pk = q4(v.x * inv) | (q4(v.y * inv) << 4)
                    | (q4(v.z * inv) << 8) | (q4(v.w * inv) << 12);
    const int addr = ((row >> 4) << 11) | ((lane >> 5) << 10) | ((row & 15) << 6)
                   | (((lane >> 3) & 3) << 4) | ((lane & 7) << 1);
    *(unsigned short*)(zn + addr) = (unsigned short)pk;
}

// ---------------- Phase 2: fp4 tiles, LDS-dedup, fused final loss ------------
// R13's proven shape at 4 blocks/CU; last finishing block computes the loss.
__global__ __launch_bounds__(256, 4) void tile_k(
    const unsigned char* __restrict__ zn,
    float* __restrict__ rowAcc,         // [8192] += sum_j exp(2 S_ij)
    float* __restrict__ posv,           // [8192] raw acc_pos
    float* __restrict__ diagE,          // [8192] exp2(acc_ii*EXP2C4)
    unsigned int* __restrict__ cnt,
    float* __restrict__ out)
{
    __shared__ unsigned char As[16384];
    __shared__ unsigned char Bs[16384];
    __shared__ float red[4];
    __shared__ bool  lastBlock;

    const int bid = blockIdx.x;
    // decode upper-triangular (rb, cb), cb >= rb; C(r) = r*(129-r)/2
    int rb = (int)((129.0f - sqrtf(16641.0f - 8.0f * (float)bid)) * 0.5f);
    rb = rb < 0 ? 0 : (rb > 63 ? 63 : rb);
    while ((rb + 1) * (129 - (rb + 1)) / 2 <= bid) ++rb;
    while (rb * (129 - rb) / 2 > bid) --rb;
    const int cb = rb + (bid - rb * (129 - rb) / 2);

    const int t      = threadIdx.x;
    const int lane   = t & 63;
    const int w      = t >> 6;
    const int wy     = w >> 1;
    const int wx     = w & 1;
    const int lane15 = lane & 15;
    const int quad   = lane >> 4;
    const int rowBase = rb * 128;
    const int colBase = cb * 128;

    // ---- stage A (and B when off-diagonal): identity copy, 4 KB per shot ----
    {
        const int off = t * 16;
        const unsigned char* gA = zn + (size_t)rb * 16384;
        #pragma unroll
        for (int s = 0; s < 4; ++s)
            async_copy16(gA + s * 4096 + off, As + s * 4096 + off);
        if (cb != rb) {
            const unsigned char* gB = zn + (size_t)cb * 16384;
            #pragma unroll
            for (int s = 0; s < 4; ++s)
                async_copy16(gB + s * 4096 + off, Bs + s * 4096 + off);
        }
    }
    __syncthreads();
    const unsigned char* Bb = (cb == rb) ? As : Bs;

    const int laneOff = lane15 * 64 + quad * 16;
    f32x4 acc[4][4];
    #pragma unroll
    for (int i = 0; i < 4; ++i)
        #pragma unroll
        for (int j = 0; j < 4; ++j)
            acc[i][j] = (f32x4){0.f, 0.f, 0.f, 0.f};

    #pragma unroll
    for (int ks = 0; ks < 2; ++ks) {
        i32x4 a[4], b[4];
        #pragma unroll
        for (int mi = 0; mi < 4; ++mi)
            a[mi] = *(const i32x4*)(As + (wy * 4 + mi) * 2048 + ks * 1024 + laneOff);
        #pragma unroll
        for (int ni = 0; ni < 4; ++ni)
            b[ni] = *(const i32x4*)(Bb + (wx * 4 + ni) * 2048 + ks * 1024 + laneOff);
        #pragma unroll
        for (int mi = 0; mi < 4; ++mi)
            #pragma unroll
            for (int ni = 0; ni < 4; ++ni)
                acc[mi][ni] = __builtin_amdgcn_mfma_scale_f32_16x16x128_f8f6f4(
                    widen(a[mi]), widen(b[ni]), acc[mi][ni],
                    4, 4, 0, SCL1, 0, SCL1);
    }

    // ---- epilogue (validated R10-R13) ----
    // C/D layout: m-row = quad*4 + reg, n-col = lane15.
    const bool diagLane = (wy == wx) && ((lane15 >> 2) == quad);
    const int  rsel = lane15 & 3;
    if (cb == rb && diagLane) {
        #pragma unroll
        for (int mi = 0; mi < 4; ++mi) {
            int grow = rowBase + wy * 64 + mi * 16 + lane15;
            diagE[grow] = fexp2(acc[mi][mi][rsel] * EXP2C4);
        }
    }
    if (cb == rb + 32 && diagLane) {         // positive-pair diagonal
        #pragma unroll
        for (int mi = 0; mi < 4; ++mi) {
            int grow = rowBase + wy * 64 + mi * 16 + lane15;
            float v = acc[mi][mi][rsel];
            posv[grow] = v;
            posv[grow + B_HALF] = v;
        }
    }

    // exp(2*S) in place (acc = 256*S)
    #pragma unroll
    for (int mi = 0; mi < 4; ++mi)
        #pragma unroll
        for (int ni = 0; ni < 4; ++ni)
            #pragma unroll
            for (int r = 0; r < 4; ++r)
                acc[mi][ni][r] = fexp2(acc[mi][ni][r] * EXP2C4);

    // row sums (over n): DPP reduce on VALU pipe; atomic from lane 15
    #pragma unroll
    for (int mi = 0; mi < 4; ++mi)
        #pragma unroll
        for (int r = 0; r < 4; ++r) {
            float s = acc[mi][0][r] + acc[mi][1][r] + acc[mi][2][r] + acc[mi][3][r];
            s = dpp_rowsum16(s);
            if (lane15 == 15)
                atomicAdd(&rowAcc[rowBase + wy * 64 + mi * 16 + quad * 4 + r], s);
        }

    // col sums (over m); off-diagonal tiles only
    if (cb != rb) {
        #pragma unroll
        for (int ni = 0; ni < 4; ++ni) {
            float s = 0.0f;
            #pragma unroll
            for (int mi = 0; mi < 4; ++mi)
                s += acc[mi][ni][0] + acc[mi][ni][1] + acc[mi][ni][2] + acc[mi][ni][3];
            s += __shfl_xor(s, 16);
            s += __shfl_xor(s, 32);
            if (quad == 0)
                atomicAdd(&rowAcc[colBase + wx * 64 + ni * 16 + lane15], s);
        }
    }

    // ---- fused final loss: last finishing block reduces all rows ----
    __threadfence();                          // publish our atomics/stores
    if (t == 0)
        lastBlock = (atomicAdd(cnt, 1u) == NUT - 1u);
    __syncthreads();
    if (!lastBlock) return;

    __threadfence();                          // acquire all blocks' results
    float sum = 0.0f;
    #pragma unroll 4
    for (int i = t; i < N_ROWS; i += 256) {
        float s = rowAcc[i] - diagE[i];                // drop main-diag term
        sum += __logf(s) - posv[i] * 0.0078125f;       // 2*S_pos = acc_pos/128
    }
    #pragma unroll
    for (int m = 1; m < 64; m <<= 1) sum += __shfl_xor(sum, m);
    if (lane == 0) red[w] = sum;
    __syncthreads();
    if (t == 0)
        out[0] = (red[0] + red[1] + red[2] + red[3]) * (1.0f / (float)N_ROWS);
}

extern "C" void kernel_launch(void* const* d_in, const int* in_sizes, int n_in,
                              void* d_out, int out_size, void* d_ws, size_t ws_size,
                              hipStream_t stream) {
    const float* z_orig = (const float*)d_in[0];
    const float* z_aug  = (const float*)d_in[1];
    char* ws = (char*)d_ws;
    unsigned char* zn   = (unsigned char*)(ws + WS_ZN);
    float* rowAcc       = (float*)(ws + WS_ROWACC);
    float* posv         = (float*)(ws + WS_POS);
    float* diagE        = (float*)(ws + WS_DIAG);
    unsigned int* cnt   = (unsigned int*)(ws + WS_CNT);

    normalize_k<<<N_ROWS / 4, 256, 0, stream>>>(z_orig, z_aug, zn, rowAcc, cnt);
    tile_k<<<NUT, 256, 0, stream>>>(zn, rowAcc, posv, diagE, cnt, (float*)d_out);
}

// Round 15
// 88.156 us; speedup vs baseline: 2.3073x; 2.3073x over previous
//
#include <hip/hip_runtime.h>
#include <hip/hip_bf16.h>

typedef __attribute__((ext_vector_type(4))) float f32x4;
typedef __attribute__((ext_vector_type(4))) int   i32x4;
typedef __attribute__((ext_vector_type(8))) int   i32x8;

#define N_ROWS 8192
#define B_HALF 4096
#define NUT   2080          // 64*65/2 upper-triangle 128x128 tiles
// exp(2S) where acc = 256*S (inputs pre-scaled x16): exp2(acc * 2*log2e/256)
#define EXP2C4 0.01127105500694503f
#define SCL1   0x7F7F7F7Fu  // E8M0 127 in all bytes -> scale 1.0

// ws layout (bytes)
#define WS_ZN       0                    // fp4 frag-major [512 groups][2048 B] = 1 MB
#define WS_ROWACC   2097152              // float[8192]  sum_j exp(2 S_ij)
#define WS_POS      2129920              // float[8192]  raw acc_pos (= 256*S_pos)
#define WS_DIAG     2162688              // float[8192]  exp2(acc_ii*EXP2C4)
#define WS_ACC      2195456              // float final accum
#define WS_CNT      2195460              // uint  block counter

__device__ __forceinline__ float fexp2(float x) {
#if __has_builtin(__builtin_amdgcn_exp2f)
    return __builtin_amdgcn_exp2f(x);
#else
    return exp2f(x);
#endif
}

// round-to-nearest e2m1 code (values 0,.5,1,1.5,2,3,4,6), sign in bit 3
__device__ __forceinline__ unsigned int q4(float x) {
    float a = fabsf(x);
    unsigned int s = (__float_as_uint(x) >> 31) << 3;
    unsigned int c = a < 0.25f ? 0u : a < 0.75f ? 1u : a < 1.25f ? 2u
                   : a < 1.75f ? 3u : a < 2.5f  ? 4u : a < 3.5f  ? 5u
                   : a < 5.0f  ? 6u : 7u;
    return c | s;
}

__device__ __forceinline__ i32x8 widen(i32x4 v) {
    return (i32x8){v.x, v.y, v.z, v.w, 0, 0, 0, 0};
}

// 16-lane row sum on the VALU pipe (DPP row_shr). Result in lane 15 of row.
__device__ __forceinline__ float dpp_rowsum16(float x) {
    x += __int_as_float(__builtin_amdgcn_update_dpp(
             0, __float_as_int(x), 0x111, 0xF, 0xF, true));   // row_shr:1
    x += __int_as_float(__builtin_amdgcn_update_dpp(
             0, __float_as_int(x), 0x112, 0xF, 0xF, true));   // row_shr:2
    x += __int_as_float(__builtin_amdgcn_update_dpp(
             0, __float_as_int(x), 0x114, 0xF, 0xF, true));   // row_shr:4
    x += __int_as_float(__builtin_amdgcn_update_dpp(
             0, __float_as_int(x), 0x118, 0xF, 0xF, true));   // row_shr:8
    return x;
}

__device__ __forceinline__ void async_copy16(const void* g, void* l) {
    __builtin_amdgcn_global_load_lds(
        (const __attribute__((address_space(1))) unsigned int*)g,
        (__attribute__((address_space(3))) unsigned int*)l,
        16, 0, 0);
}

// ---------------- Phase 1: normalize -> fp4 (x16), FRAGMENT-MAJOR ------------
// (validated R10-R14)
__global__ __launch_bounds__(256) void normalize_k(
    const float* __restrict__ z_orig, const float* __restrict__ z_aug,
    unsigned char* __restrict__ zn, float* __restrict__ rowAcc,
    float* __restrict__ accum, unsigned int* __restrict__ cnt)
{
    if (blockIdx.x == 0 && threadIdx.x == 0) { *accum = 0.0f; *cnt = 0u; }
    const int row  = blockIdx.x * 4 + (threadIdx.x >> 6);
    const int lane = threadIdx.x & 63;
    if (lane == 0) rowAcc[row] = 0.0f;       // zeroed before tile_k (stream order)
    const float* src = (row < B_HALF) ? (z_aug  + (size_t)row * 256)
                                      : (z_orig + (size_t)(row - B_HALF) * 256);
    float4 v = ((const float4*)src)[lane];
    float ss = v.x*v.x + v.y*v.y + v.z*v.z + v.w*v.w;
    #pragma unroll
    for (int m = 1; m < 64; m <<= 1) ss += __shfl_xor(ss, m);
    float inv = 16.0f / fmaxf(sqrtf(ss), 1e-8f);   // x16 pre-scale into e2m1 range
    unsigned int pk = q4(v.x * inv) | (q4(v.y * inv) << 4)
                    | (q4(v.z * inv) << 8) | (q4(v.w * inv) << 12);
    const int addr = ((row >> 4) << 11) | ((lane >> 5) << 10) | ((row & 15) << 6)
                   | (((lane >> 3) & 3) << 4) | ((lane & 7) << 1);
    *(unsigned short*)(zn + addr) = (unsigned short)pk;
}

// ---------------- Phase 2: fp4 128x128 tiles, LDS-dedup staging --------------
// R13's proven shape; single variable change: min-waves 3 -> 4 (occupancy
// lever, shown spill-free in R14's allocation). NO device fences in here
// (R14 lesson: per-block __threadfence = L2 flush storm, 5x regression).
__global__ __launch_bounds__(256, 4) void tile_k(
    const unsigned char* __restrict__ zn,
    float* __restrict__ rowAcc,         // [8192] += sum_j exp(2 S_ij)
    float* __restrict__ posv,           // [8192] raw acc_pos
    float* __restrict__ diagE)          // [8192] exp2(acc_ii*EXP2C4)
{
    __shared__ unsigned char As[16384];
    __shared__ unsigned char Bs[16384];

    const int bid = blockIdx.x;
    // decode upper-triangular (rb, cb), cb >= rb; C(r) = r*(129-r)/2
    int rb = (int)((129.0f - sqrtf(16641.0f - 8.0f * (float)bid)) * 0.5f);
    rb = rb < 0 ? 0 : (rb > 63 ? 63 : rb);
    while ((rb + 1) * (129 - (rb + 1)) / 2 <= bid) ++rb;
    while (rb * (129 - rb) / 2 > bid) --rb;
    const int cb = rb + (bid - rb * (129 - rb) / 2);

    const int t      = threadIdx.x;
    const int lane   = t & 63;
    const int w      = t >> 6;
    const int wy     = w >> 1;
    const int wx     = w & 1;
    const int lane15 = lane & 15;
    const int quad   = lane >> 4;
    const int rowBase = rb * 128;
    const int colBase = cb * 128;

    // ---- stage A (and B when off-diagonal): identity copy, 4 KB per shot ----
    {
        const int off = t * 16;
        const unsigned char* gA = zn + (size_t)rb * 16384;
        #pragma unroll
        for (int s = 0; s < 4; ++s)
            async_copy16(gA + s * 4096 + off, As + s * 4096 + off);
        if (cb != rb) {
            const unsigned char* gB = zn + (size_t)cb * 16384;
            #pragma unroll
            for (int s = 0; s < 4; ++s)
                async_copy16(gB + s * 4096 + off, Bs + s * 4096 + off);
        }
    }
    __syncthreads();                         // the only barrier
    const unsigned char* Bb = (cb == rb) ? As : Bs;

    const int laneOff = lane15 * 64 + quad * 16;
    f32x4 acc[4][4];
    #pragma unroll
    for (int i = 0; i < 4; ++i)
        #pragma unroll
        for (int j = 0; j < 4; ++j)
            acc[i][j] = (f32x4){0.f, 0.f, 0.f, 0.f};

    #pragma unroll
    for (int ks = 0; ks < 2; ++ks) {
        i32x4 a[4], b[4];
        #pragma unroll
        for (int mi = 0; mi < 4; ++mi)
            a[mi] = *(const i32x4*)(As + (wy * 4 + mi) * 2048 + ks * 1024 + laneOff);
        #pragma unroll
        for (int ni = 0; ni < 4; ++ni)
            b[ni] = *(const i32x4*)(Bb + (wx * 4 + ni) * 2048 + ks * 1024 + laneOff);
        #pragma unroll
        for (int mi = 0; mi < 4; ++mi)
            #pragma unroll
            for (int ni = 0; ni < 4; ++ni)
                acc[mi][ni] = __builtin_amdgcn_mfma_scale_f32_16x16x128_f8f6f4(
                    widen(a[mi]), widen(b[ni]), acc[mi][ni],
                    4, 4, 0, SCL1, 0, SCL1);
    }

    // ---- epilogue (validated R10-R13) ----
    // C/D layout: m-row = quad*4 + reg, n-col = lane15.
    const bool diagLane = (wy == wx) && ((lane15 >> 2) == quad);
    const int  rsel = lane15 & 3;
    if (cb == rb && diagLane) {
        #pragma unroll
        for (int mi = 0; mi < 4; ++mi) {
            int grow = rowBase + wy * 64 + mi * 16 + lane15;
            diagE[grow] = fexp2(acc[mi][mi][rsel] * EXP2C4);
        }
    }
    if (cb == rb + 32 && diagLane) {         // positive-pair diagonal
        #pragma unroll
        for (int mi = 0; mi < 4; ++mi) {
            int grow = rowBase + wy * 64 + mi * 16 + lane15;
            float v = acc[mi][mi][rsel];
            posv[grow] = v;
            posv[grow + B_HALF] = v;
        }
    }

    // exp(2*S) in place (acc = 256*S)
    #pragma unroll
    for (int mi = 0; mi < 4; ++mi)
        #pragma unroll
        for (int ni = 0; ni < 4; ++ni)
            #pragma unroll
            for (int r = 0; r < 4; ++r)
                acc[mi][ni][r] = fexp2(acc[mi][ni][r] * EXP2C4);

    // row sums (over n): DPP reduce on VALU pipe; atomic from lane 15
    #pragma unroll
    for (int mi = 0; mi < 4; ++mi)
        #pragma unroll
        for (int r = 0; r < 4; ++r) {
            float s = acc[mi][0][r] + acc[mi][1][r] + acc[mi][2][r] + acc[mi][3][r];
            s = dpp_rowsum16(s);
            if (lane15 == 15)
                atomicAdd(&rowAcc[rowBase + wy * 64 + mi * 16 + quad * 4 + r], s);
        }

    // col sums (over m); off-diagonal tiles only
    if (cb != rb) {
        #pragma unroll
        for (int ni = 0; ni < 4; ++ni) {
            float s = 0.0f;
            #pragma unroll
            for (int mi = 0; mi < 4; ++mi)
                s += acc[mi][ni][0] + acc[mi][ni][1] + acc[mi][ni][2] + acc[mi][ni][3];
            s += __shfl_xor(s, 16);
            s += __shfl_xor(s, 32);
            if (quad == 0)
                atomicAdd(&rowAcc[colBase + wx * 64 + ni * 16 + lane15], s);
        }
    }
}

// ---------------- Phase 3: per-row loss + grid reduction (last block) --------
__global__ __launch_bounds__(256) void loss_k(
    const float* __restrict__ rowAcc, const float* __restrict__ posv,
    const float* __restrict__ diagE, float* __restrict__ accum,
    unsigned int* __restrict__ cnt, float* __restrict__ out)
{
    const int i = blockIdx.x * 256 + threadIdx.x;
    float s = rowAcc[i] - diagE[i];                 // drop main-diagonal term
    float loss = __logf(s) - posv[i] * 0.0078125f;  // 2*S_pos = acc_pos/128

    #pragma unroll
    for (int m = 1; m < 64; m <<= 1) loss += __shfl_xor(loss, m);
    __shared__ float red[4];
    if ((threadIdx.x & 63) == 0) red[threadIdx.x >> 6] = loss;
    __syncthreads();
    if (threadIdx.x == 0) {
        float bs = red[0] + red[1] + red[2] + red[3];
        atomicAdd(accum, bs);
        __threadfence();
        unsigned int old = atomicAdd(cnt, 1u);
        if (old == 31u) {                       // last of 32 blocks
            __threadfence();
            float total = atomicAdd(accum, 0.0f);
            out[0] = total * (1.0f / (float)N_ROWS);
        }
    }
}

extern "C" void kernel_launch(void* const* d_in, const int* in_sizes, int n_in,
                              void* d_out, int out_size, void* d_ws, size_t ws_size,
                              hipStream_t stream) {
    const float* z_orig = (const float*)d_in[0];
    const float* z_aug  = (const float*)d_in[1];
    char* ws = (char*)d_ws;
    unsigned char* zn   = (unsigned char*)(ws + WS_ZN);
    float* rowAcc       = (float*)(ws + WS_ROWACC);
    float* posv         = (float*)(ws + WS_POS);
    float* diagE        = (float*)(ws + WS_DIAG);
    float* accum        = (float*)(ws + WS_ACC);
    unsigned int* cnt   = (unsigned int*)(ws + WS_CNT);

    normalize_k<<<N_ROWS / 4, 256, 0, stream>>>(z_orig, z_aug, zn, rowAcc, accum, cnt);
    tile_k<<<NUT, 256, 0, stream>>>(zn, rowAcc, posv, diagE);
    loss_k<<<N_ROWS / 256, 256, 0, stream>>>(rowAcc, posv, diagE, accum, cnt,
                                             (float*)d_out);
}